// Round 5
// baseline (725.348 us; speedup 1.0000x reference)
//
#include <hip/hip_runtime.h>
#include <math.h>

// Problem constants
#define NB 8        // batch
#define NC 256      // channels (DIM)
#define NPIX 4096   // H*W
#define NO3 1536    // 3*HIDDEN
#define NHID 512    // HIDDEN
#define NHEADS 8
#define NDH 64

// Workspace layout (float offsets). Total = 2097152 + 50331648 floats ~= 210 MB.
#define WS_S     0          // [NB*NPIX]        per-pixel input scale
#define WS_KMAX  40960      // [NB*NHID]        k row max
#define WS_KSUM  49152      // [NB*NHID]        k row sum-exp
#define WS_CTXP  65536      // [4][64][64][64]  context partials
#define WS_QKV   2097152    // [NB][1536][4096] qkv (q softmaxed in place; PV out overwrites k rows)

// ---------------------------------------------------------------- K1: s[b,n] = 16 / max(||x[:,n]||, eps)
__global__ __launch_bounds__(256) void k_pixel_scale(const float* __restrict__ x, float* __restrict__ s) {
    int idx = blockIdx.x * 256 + threadIdx.x;      // b*NPIX + n
    int b = idx >> 12, n = idx & 4095;
    const float* xp = x + (size_t)b * NC * NPIX + n;
    float acc = 0.f;
    #pragma unroll 8
    for (int c = 0; c < NC; ++c) { float v = xp[(size_t)c * NPIX]; acc = fmaf(v, v, acc); }
    s[idx] = 16.0f / fmaxf(sqrtf(acc), 1e-12f);
}

// ---------------------------------------------------------------- K2: qkv[b,o,n] = s[b,n] * sum_c (wq[o,c]*norm_w[c]) * x[b,c,n]
__global__ __launch_bounds__(256) void k_qkv_gemm(const float* __restrict__ x, const float* __restrict__ wq,
                                                  const float* __restrict__ norm_w, const float* __restrict__ s,
                                                  float* __restrict__ qkv) {
    __shared__ float As[16][68];   // [k][m], stride 68 breaks pow2 bank patterns
    __shared__ float Bs[16][68];   // [k][n]
    int b = blockIdx.z;
    int m0 = blockIdx.y * 64;
    int n0 = blockIdx.x * 64;
    int tid = threadIdx.x;
    int tx = tid & 15, ty = tid >> 4;
    const float* xb = x + (size_t)b * NC * NPIX;
    float acc[4][4] = {{0.f}};
    int ar = tid >> 4, ac = tid & 15;
    int br = tid >> 6, bc = tid & 63;
    for (int k0 = 0; k0 < NC; k0 += 16) {
        float nw = norm_w[k0 + ac];
        #pragma unroll
        for (int i = 0; i < 4; ++i) {
            int m = ar + i * 16;
            As[ac][m] = wq[(size_t)(m0 + m) * NC + k0 + ac] * nw;
        }
        #pragma unroll
        for (int i = 0; i < 4; ++i) {
            int k = br + i * 4;
            Bs[k][bc] = xb[(size_t)(k0 + k) * NPIX + n0 + bc];
        }
        __syncthreads();
        #pragma unroll
        for (int k = 0; k < 16; ++k) {
            float a[4], bv[4];
            #pragma unroll
            for (int i = 0; i < 4; ++i) a[i] = As[k][ty * 4 + i];
            #pragma unroll
            for (int j = 0; j < 4; ++j) bv[j] = Bs[k][tx * 4 + j];
            #pragma unroll
            for (int i = 0; i < 4; ++i) {
                #pragma unroll
                for (int j = 0; j < 4; ++j) acc[i][j] = fmaf(a[i], bv[j], acc[i][j]);
            }
        }
        __syncthreads();
    }
    float sc[4];
    #pragma unroll
    for (int j = 0; j < 4; ++j) sc[j] = s[b * NPIX + n0 + tx * 4 + j];
    #pragma unroll
    for (int i = 0; i < 4; ++i) {
        size_t ro = ((size_t)b * NO3 + m0 + ty * 4 + i) * NPIX + n0 + tx * 4;
        #pragma unroll
        for (int j = 0; j < 4; ++j) qkv[ro + j] = acc[i][j] * sc[j];
    }
}

// ---------------------------------------------------------------- K3: q = softmax over dh (64 rows) * 1/8, in place
__global__ __launch_bounds__(256) void k_q_softmax(float* __restrict__ qkv) {
    int idx = blockIdx.x * 256 + threadIdx.x;      // (b*8+h)*NPIX + n
    int n = idx & 4095;
    int bh = idx >> 12;
    int b = bh >> 3, h = bh & 7;
    float* qp = qkv + ((size_t)b * NO3 + h * NDH) * NPIX + n;
    float v[64];
    float mx = -1e30f;
    #pragma unroll
    for (int d = 0; d < 64; ++d) { v[d] = qp[(size_t)d * NPIX]; mx = fmaxf(mx, v[d]); }
    float sum = 0.f;
    #pragma unroll
    for (int d = 0; d < 64; ++d) { v[d] = __expf(v[d] - mx); sum += v[d]; }
    float inv = 0.125f / sum;   // * dh^-0.5 = 1/8
    #pragma unroll
    for (int d = 0; d < 64; ++d) qp[(size_t)d * NPIX] = v[d] * inv;
}

// ---------------------------------------------------------------- K4: per k-row (b,h,d): max and sum-exp over 4104 (8 mem + 4096)
__global__ __launch_bounds__(256) void k_k_stats(const float* __restrict__ qkv, const float* __restrict__ mem_kv,
                                                 float* __restrict__ kmax, float* __restrict__ ksum) {
    int row = blockIdx.x;                          // b*512 + hd
    int b = row >> 9, hd = row & 511;
    int h = hd >> 6, d = hd & 63;
    const float* kp = qkv + ((size_t)b * NO3 + NHID + hd) * NPIX;
    int t = threadIdx.x;
    float m = -1e30f, sum = 0.f;
    for (int n = t; n < NPIX; n += 256) {
        float v = kp[n];
        if (v > m) { sum *= __expf(m - v); m = v; }
        sum += __expf(v - m);
    }
    if (t < 8) {
        float v = mem_kv[((size_t)h * 64 + d) * 8 + t];   // mem_kv[0]
        if (v > m) { sum *= __expf(m - v); m = v; }
        sum += __expf(v - m);
    }
    __shared__ float sm[256], ss[256];
    sm[t] = m; ss[t] = sum;
    __syncthreads();
    for (int st = 128; st > 0; st >>= 1) {
        if (t < st) {
            float m1 = sm[t], m2 = sm[t + st];
            float s1 = ss[t], s2 = ss[t + st];
            float mm = fmaxf(m1, m2);
            sm[t] = mm;
            ss[t] = s1 * __expf(m1 - mm) + s2 * __expf(m2 - mm);
        }
        __syncthreads();
    }
    if (t == 0) { kmax[row] = sm[0]; ksum[row] = ss[0]; }
}

// ---------------------------------------------------------------- K5: context partials: ctx[d,e] += sum_n k'[d,n]*v[e,n]
__global__ __launch_bounds__(256) void k_context(const float* __restrict__ qkv, const float* __restrict__ mem_kv,
                                                 const float* __restrict__ kmax, const float* __restrict__ ksum,
                                                 float* __restrict__ ctxp) {
    int bh = blockIdx.x;                            // b*8+h
    int p = blockIdx.y;                             // n-range partial 0..3
    int b = bh >> 3, h = bh & 7;
    const float* kp = qkv + ((size_t)b * NO3 + NHID + h * NDH) * NPIX;
    const float* vp = qkv + ((size_t)b * NO3 + 2 * NHID + h * NDH) * NPIX;
    __shared__ float KsT[64][68];   // [n][d] transposed for float4 reads
    __shared__ float VsT[64][68];   // [n][e]
    __shared__ float smx[64], sinv[64];
    int t = threadIdx.x;
    if (t < 64) { smx[t] = kmax[bh * 64 + t]; sinv[t] = 1.0f / ksum[bh * 64 + t]; }
    __syncthreads();
    int tx = t & 15, ty = t >> 4;
    int d0 = ty * 4, e0 = tx * 4;
    float acc[4][4] = {{0.f}};
    if (p == 0) {   // 8 memory columns
        const float* mkp = mem_kv + (size_t)h * 64 * 8;
        const float* mvp = mem_kv + (size_t)NHEADS * 64 * 8 + (size_t)h * 64 * 8;
        #pragma unroll
        for (int j = 0; j < 8; ++j) {
            float vv[4];
            #pragma unroll
            for (int q = 0; q < 4; ++q) vv[q] = mvp[(e0 + q) * 8 + j];
            #pragma unroll
            for (int i = 0; i < 4; ++i) {
                float kk = __expf(mkp[(d0 + i) * 8 + j] - smx[d0 + i]) * sinv[d0 + i];
                #pragma unroll
                for (int q = 0; q < 4; ++q) acc[i][q] = fmaf(kk, vv[q], acc[i][q]);
            }
        }
    }
    int rr = t >> 6, cc = t & 63;
    for (int n0 = p * 1024; n0 < p * 1024 + 1024; n0 += 64) {
        #pragma unroll
        for (int i = 0; i < 16; ++i) {
            int row = rr + i * 4;
            float kv = kp[(size_t)row * NPIX + n0 + cc];
            KsT[cc][row] = __expf(kv - smx[row]) * sinv[row];
            VsT[cc][row] = vp[(size_t)row * NPIX + n0 + cc];
        }
        __syncthreads();
        #pragma unroll 4
        for (int n = 0; n < 64; ++n) {
            float4 a = *(const float4*)&KsT[n][d0];
            float4 vv = *(const float4*)&VsT[n][e0];
            float av[4] = {a.x, a.y, a.z, a.w};
            float vvv[4] = {vv.x, vv.y, vv.z, vv.w};
            #pragma unroll
            for (int i = 0; i < 4; ++i) {
                #pragma unroll
                for (int q = 0; q < 4; ++q) acc[i][q] = fmaf(av[i], vvv[q], acc[i][q]);
            }
        }
        __syncthreads();
    }
    #pragma unroll
    for (int i = 0; i < 4; ++i) {
        #pragma unroll
        for (int q = 0; q < 4; ++q)
            ctxp[(((size_t)p * 64 + bh) * 64 + d0 + i) * 64 + e0 + q] = acc[i][q];
    }
}

// ---------------------------------------------------------------- K6: out'[e,n] = sum_d ctx[d,e]*q'[d,n]; written over dead k rows
__global__ __launch_bounds__(256) void k_pv(float* __restrict__ qkv, const float* __restrict__ ctxp) {
    int nb = blockIdx.x;                            // 16 column blocks of 256
    int bh = blockIdx.y;
    int b = bh >> 3, h = bh & 7;
    __shared__ float Cs[64][64];                    // broadcast reads -> no conflict, unpadded for float4
    int t = threadIdx.x;
    for (int i = t; i < 4096; i += 256) {
        float v = 0.f;
        #pragma unroll
        for (int p = 0; p < 4; ++p) v += ctxp[((size_t)p * 64 + bh) * 4096 + i];
        Cs[i >> 6][i & 63] = v;
    }
    __syncthreads();
    int n = nb * 256 + t;
    const float* qp = qkv + ((size_t)b * NO3 + h * NDH) * NPIX + n;
    float acc[64];
    #pragma unroll
    for (int e = 0; e < 64; ++e) acc[e] = 0.f;
    #pragma unroll 2
    for (int d = 0; d < 64; ++d) {
        float qv = qp[(size_t)d * NPIX];
        const float4* crow = (const float4*)&Cs[d][0];
        #pragma unroll
        for (int e4 = 0; e4 < 16; ++e4) {
            float4 cv = crow[e4];
            acc[e4 * 4 + 0] = fmaf(cv.x, qv, acc[e4 * 4 + 0]);
            acc[e4 * 4 + 1] = fmaf(cv.y, qv, acc[e4 * 4 + 1]);
            acc[e4 * 4 + 2] = fmaf(cv.z, qv, acc[e4 * 4 + 2]);
            acc[e4 * 4 + 3] = fmaf(cv.w, qv, acc[e4 * 4 + 3]);
        }
    }
    float* op = qkv + ((size_t)b * NO3 + NHID + h * NDH) * NPIX + n;
    #pragma unroll
    for (int e = 0; e < 64; ++e) op[(size_t)e * NPIX] = acc[e];
}

// ---------------------------------------------------------------- K7: out[b,o,n] = sum_c2 wo[o,c2]*out'[b,c2,n] + bo[o]
__global__ __launch_bounds__(256) void k_out_gemm(const float* __restrict__ qkv, const float* __restrict__ wo,
                                                  const float* __restrict__ bo, float* __restrict__ out) {
    __shared__ float As[16][68];
    __shared__ float Bs[16][68];
    int b = blockIdx.z;
    int m0 = blockIdx.y * 64;
    int n0 = blockIdx.x * 64;
    int tid = threadIdx.x;
    int tx = tid & 15, ty = tid >> 4;
    const float* xb = qkv + ((size_t)b * NO3 + NHID) * NPIX;   // out' lives in k rows
    float acc[4][4] = {{0.f}};
    int ar = tid >> 4, ac = tid & 15;
    int br = tid >> 6, bc = tid & 63;
    for (int k0 = 0; k0 < NHID; k0 += 16) {
        #pragma unroll
        for (int i = 0; i < 4; ++i) {
            int m = ar + i * 16;
            As[ac][m] = wo[(size_t)(m0 + m) * NHID + k0 + ac];
        }
        #pragma unroll
        for (int i = 0; i < 4; ++i) {
            int k = br + i * 4;
            Bs[k][bc] = xb[(size_t)(k0 + k) * NPIX + n0 + bc];
        }
        __syncthreads();
        #pragma unroll
        for (int k = 0; k < 16; ++k) {
            float a[4], bv[4];
            #pragma unroll
            for (int i = 0; i < 4; ++i) a[i] = As[k][ty * 4 + i];
            #pragma unroll
            for (int j = 0; j < 4; ++j) bv[j] = Bs[k][tx * 4 + j];
            #pragma unroll
            for (int i = 0; i < 4; ++i) {
                #pragma unroll
                for (int j = 0; j < 4; ++j) acc[i][j] = fmaf(a[i], bv[j], acc[i][j]);
            }
        }
        __syncthreads();
    }
    #pragma unroll
    for (int i = 0; i < 4; ++i) {
        float bias = bo[m0 + ty * 4 + i];
        size_t ro = ((size_t)b * NC + m0 + ty * 4 + i) * NPIX + n0 + tx * 4;
        #pragma unroll
        for (int j = 0; j < 4; ++j) out[ro + j] = acc[i][j] + bias;
    }
}

// ---------------------------------------------------------------- K8: final RMS norm over 256 channels, in place on d_out
__global__ __launch_bounds__(256) void k_out_norm(float* __restrict__ out, const float* __restrict__ onw) {
    int idx = blockIdx.x * 256 + threadIdx.x;
    int b = idx >> 12, n = idx & 4095;
    float* op = out + (size_t)b * NC * NPIX + n;
    float acc = 0.f;
    #pragma unroll 8
    for (int c = 0; c < NC; ++c) { float v = op[(size_t)c * NPIX]; acc = fmaf(v, v, acc); }
    float sc = 16.0f / fmaxf(sqrtf(acc), 1e-12f);
    #pragma unroll 8
    for (int c = 0; c < NC; ++c) op[(size_t)c * NPIX] = op[(size_t)c * NPIX] * (sc * onw[c]);
}

extern "C" void kernel_launch(void* const* d_in, const int* in_sizes, int n_in,
                              void* d_out, int out_size, void* d_ws, size_t ws_size,
                              hipStream_t stream) {
    const float* x      = (const float*)d_in[0];
    const float* norm_w = (const float*)d_in[1];
    const float* w_qkv  = (const float*)d_in[2];
    const float* mem_kv = (const float*)d_in[3];
    const float* w_out  = (const float*)d_in[4];
    const float* b_out  = (const float*)d_in[5];
    const float* onw    = (const float*)d_in[6];
    float* out = (float*)d_out;
    float* ws  = (float*)d_ws;

    float* s    = ws + WS_S;
    float* kmax = ws + WS_KMAX;
    float* ksum = ws + WS_KSUM;
    float* ctxp = ws + WS_CTXP;
    float* qkv  = ws + WS_QKV;

    k_pixel_scale<<<dim3(NB * NPIX / 256), dim3(256), 0, stream>>>(x, s);
    k_qkv_gemm<<<dim3(NPIX / 64, NO3 / 64, NB), dim3(256), 0, stream>>>(x, w_qkv, norm_w, s, qkv);
    k_q_softmax<<<dim3(NB * NHEADS * NPIX / 256), dim3(256), 0, stream>>>(qkv);
    k_k_stats<<<dim3(NB * NHID), dim3(256), 0, stream>>>(qkv, mem_kv, kmax, ksum);
    k_context<<<dim3(NB * NHEADS, 4), dim3(256), 0, stream>>>(qkv, mem_kv, kmax, ksum, ctxp);
    k_pv<<<dim3(16, NB * NHEADS), dim3(256), 0, stream>>>(qkv, ctxp);
    k_out_gemm<<<dim3(NPIX / 64, NC / 64, NB), dim3(256), 0, stream>>>(qkv, w_out, b_out, out);
    k_out_norm<<<dim3(NB * NPIX / 256), dim3(256), 0, stream>>>(out, onw);
}

// Round 7
// 341.170 us; speedup vs baseline: 2.1261x; 2.1261x over previous
//
#include <hip/hip_runtime.h>
#include <math.h>

// Problem constants
#define NB 8        // batch
#define NC 256      // channels (DIM)
#define NPIX 4096   // H*W
#define NO3 1536    // 3*HIDDEN
#define NHID 512    // HIDDEN
#define NHEADS 8
#define NDH 64

typedef unsigned short u16;
typedef __attribute__((ext_vector_type(8))) short short8;
typedef __attribute__((ext_vector_type(4))) float f32x4;

// Workspace layout (float offsets). qkv stays fp32 (precision guard for softmaxes).
// xbfT (bf16, 16.8MB) lives in d_out (dead until GEMM2 writes it) to stay under ws budget.
// outT (bf16, [n][c2]) lives in the dead k-region of qkv after k_context consumes k.
#define WS_KMAX  0          // [NB*NHID]
#define WS_KSUM  4096       // [NB*NHID]
#define WS_CTXP  8192       // [4][64][64][64]
#define WS_WQBF  1056768    // ushort[1536*256]  (as float region: 196608)
#define WS_WOBF  1253376    // ushort[256*512]   (as float region: 65536)
#define WS_QKV   1318912    // [NB][1536][4096] fp32
// total = 1318912 + 50331648 = 51,650,560 floats ~= 206.6 MB (< proven 209.7 MB)

__device__ __forceinline__ u16 f2bf(float f) {
    unsigned u = __builtin_bit_cast(unsigned, f);
    unsigned r = (u + 0x7FFFu + ((u >> 16) & 1u)) >> 16;   // RTN-even
    return (u16)r;
}

typedef const __attribute__((address_space(1))) unsigned int guint;
typedef __attribute__((address_space(3))) unsigned int luint;

// ---------------------------------------------------------------- K1: fused pixel-scale + transpose + bf16 convert
// xbfT[b][n][c] = bf16( x[b][c][n] * norm_w[c] * 16/max(||x[:,n]||,eps) )
__global__ __launch_bounds__(256) void k_scale_convert(const float* __restrict__ x,
                                                        const float* __restrict__ norm_w,
                                                        u16* __restrict__ xbfT) {
    __shared__ float xs[64][257];   // raw x, [pixel][chan]; 257 breaks bank patterns
    __shared__ float red[4][64];
    __shared__ float ssh[64];
    int blk = blockIdx.x;           // b*64 + nchunk
    int b = blk >> 6;
    int n0 = (blk & 63) * 64;
    const float* xb = x + (size_t)b * NC * NPIX;
    int t = threadIdx.x;
    int p = t & 63, q = t >> 6;
    float accv = 0.f;
    #pragma unroll 8
    for (int c = q * 64; c < q * 64 + 64; ++c) {
        float v = xb[(size_t)c * NPIX + n0 + p];
        xs[p][c] = v;
        accv = fmaf(v, v, accv);
    }
    red[q][p] = accv;
    __syncthreads();
    if (t < 64) {
        float sum = red[0][t] + red[1][t] + red[2][t] + red[3][t];
        ssh[t] = 16.0f / fmaxf(sqrtf(sum), 1e-12f);
    }
    __syncthreads();
    int p2 = t >> 2, cbase = (t & 3) * 64;
    float sc = ssh[p2];
    u16* orow = xbfT + (size_t)(b * NPIX + n0 + p2) * NC + cbase;
    #pragma unroll
    for (int j = 0; j < 64; j += 8) {
        union { u16 us[8]; uint4 v; } pk;
        #pragma unroll
        for (int u = 0; u < 8; ++u)
            pk.us[u] = f2bf(xs[p2][cbase + j + u] * norm_w[cbase + j + u] * sc);
        *(uint4*)(orow + j) = pk.v;
    }
}

// ---------------------------------------------------------------- K2: weight bf16 convert (wq and wo)
__global__ __launch_bounds__(256) void k_wconv(const float* __restrict__ wq, const float* __restrict__ wo,
                                                u16* __restrict__ wqbf, u16* __restrict__ wobf) {
    int idx = blockIdx.x * 256 + threadIdx.x;
    int e = idx * 4;                                  // 524288 total elems
    if (e < 393216) {
        float4 v = *(const float4*)(wq + e);
        union { u16 us[4]; uint2 v2; } pk;
        pk.us[0] = f2bf(v.x); pk.us[1] = f2bf(v.y); pk.us[2] = f2bf(v.z); pk.us[3] = f2bf(v.w);
        *(uint2*)(wqbf + e) = pk.v2;
    } else {
        int e2 = e - 393216;
        float4 v = *(const float4*)(wo + e2);
        union { u16 us[4]; uint2 v2; } pk;
        pk.us[0] = f2bf(v.x); pk.us[1] = f2bf(v.y); pk.us[2] = f2bf(v.z); pk.us[3] = f2bf(v.w);
        *(uint2*)(wobf + e2) = pk.v2;
    }
}

// ---------------------------------------------------------------- MFMA NT-GEMM (m97 structure):
// C[b][m][n] = sum_k A[m][k]*B[b][n][k] (+bias[m]); A,B bf16 K-contiguous; C fp32, n-contiguous stride 4096.
// 128x128 tile, 4 waves (2x2 of 64x64), BK=64, global_load_lds width 16, linear LDS.
template<int KD, bool BIAS>
__global__ __launch_bounds__(256) void k_mfma_nt(const u16* __restrict__ A, const u16* __restrict__ B,
                                                  const float* __restrict__ bias, float* __restrict__ C,
                                                  size_t bStride, size_t cStride) {
    __shared__ u16 lA[128 * 64];
    __shared__ u16 lB[128 * 64];
    const int b = blockIdx.z;
    const int m0 = blockIdx.y * 128;
    const int n0 = blockIdx.x * 128;
    const u16* Bb = B + (size_t)b * bStride;
    float* Cb = C + (size_t)b * cStride;
    const int t = threadIdx.x;
    const int lane = t & 63;
    const int wid = t >> 6;
    const int wr = (wid >> 1) * 64;   // wave row (m) offset in tile
    const int wc = (wid & 1) * 64;    // wave col (n) offset
    const int fr = lane & 15;
    const int fq = lane >> 4;

    f32x4 acc[4][4];
    #pragma unroll
    for (int i = 0; i < 4; ++i)
        #pragma unroll
        for (int j = 0; j < 4; ++j) acc[i][j] = (f32x4){0.f, 0.f, 0.f, 0.f};

    for (int k0 = 0; k0 < KD; k0 += 64) {
        #pragma unroll
        for (int i = 0; i < 4; ++i) {
            int idx = i * 256 + t;
            int row = idx >> 3;            // 0..127
            int col = (idx & 7) * 8;       // ushort offset within 64-wide k row
            __builtin_amdgcn_global_load_lds((guint*)(A + (size_t)(m0 + row) * KD + k0 + col),
                                             (luint*)(&lA[idx * 8]), 16, 0, 0);
            __builtin_amdgcn_global_load_lds((guint*)(Bb + (size_t)(n0 + row) * KD + k0 + col),
                                             (luint*)(&lB[idx * 8]), 16, 0, 0);
        }
        __syncthreads();   // drains vmcnt (compiler inserts s_waitcnt before s_barrier)
        #pragma unroll
        for (int kk = 0; kk < 2; ++kk) {
            short8 af[4], bfv[4];
            #pragma unroll
            for (int i = 0; i < 4; ++i)
                af[i] = *(const short8*)&lA[(wr + i * 16 + fr) * 64 + kk * 32 + fq * 8];
            #pragma unroll
            for (int j = 0; j < 4; ++j)
                bfv[j] = *(const short8*)&lB[(wc + j * 16 + fr) * 64 + kk * 32 + fq * 8];
            #pragma unroll
            for (int i = 0; i < 4; ++i)
                #pragma unroll
                for (int j = 0; j < 4; ++j)
                    acc[i][j] = __builtin_amdgcn_mfma_f32_16x16x32_bf16(af[i], bfv[j], acc[i][j], 0, 0, 0);
        }
        __syncthreads();
    }
    // C/D layout: col = lane&15, row = (lane>>4)*4 + reg  [m89-verified]
    #pragma unroll
    for (int i = 0; i < 4; ++i) {
        int rbase = m0 + wr + i * 16 + fq * 4;
        #pragma unroll
        for (int j = 0; j < 4; ++j) {
            int c = n0 + wc + j * 16 + fr;
            #pragma unroll
            for (int r = 0; r < 4; ++r) {
                float v = acc[i][j][r];
                if (BIAS) v += bias[rbase + r];
                Cb[(size_t)(rbase + r) * NPIX + c] = v;
            }
        }
    }
}

// ---------------------------------------------------------------- K3: q = softmax over dh (64 rows) * 1/8, in place
__global__ __launch_bounds__(256) void k_q_softmax(float* __restrict__ qkv) {
    int idx = blockIdx.x * 256 + threadIdx.x;
    int n = idx & 4095;
    int bh = idx >> 12;
    int b = bh >> 3, h = bh & 7;
    float* qp = qkv + ((size_t)b * NO3 + h * NDH) * NPIX + n;
    float v[64];
    float mx = -1e30f;
    #pragma unroll
    for (int d = 0; d < 64; ++d) { v[d] = qp[(size_t)d * NPIX]; mx = fmaxf(mx, v[d]); }
    float sum = 0.f;
    #pragma unroll
    for (int d = 0; d < 64; ++d) { v[d] = __expf(v[d] - mx); sum += v[d]; }
    float inv = 0.125f / sum;
    #pragma unroll
    for (int d = 0; d < 64; ++d) qp[(size_t)d * NPIX] = v[d] * inv;
}

// ---------------------------------------------------------------- K4: k-row stats over 4104
__global__ __launch_bounds__(256) void k_k_stats(const float* __restrict__ qkv, const float* __restrict__ mem_kv,
                                                 float* __restrict__ kmax, float* __restrict__ ksum) {
    int row = blockIdx.x;
    int b = row >> 9, hd = row & 511;
    int h = hd >> 6, d = hd & 63;
    const float* kp = qkv + ((size_t)b * NO3 + NHID + hd) * NPIX;
    int t = threadIdx.x;
    float m = -1e30f, sum = 0.f;
    for (int n = t; n < NPIX; n += 256) {
        float v = kp[n];
        if (v > m) { sum *= __expf(m - v); m = v; }
        sum += __expf(v - m);
    }
    if (t < 8) {
        float v = mem_kv[((size_t)h * 64 + d) * 8 + t];
        if (v > m) { sum *= __expf(m - v); m = v; }
        sum += __expf(v - m);
    }
    __shared__ float sm[256], ss[256];
    sm[t] = m; ss[t] = sum;
    __syncthreads();
    for (int st = 128; st > 0; st >>= 1) {
        if (t < st) {
            float m1 = sm[t], m2 = sm[t + st];
            float s1 = ss[t], s2 = ss[t + st];
            float mm = fmaxf(m1, m2);
            sm[t] = mm;
            ss[t] = s1 * __expf(m1 - mm) + s2 * __expf(m2 - mm);
        }
        __syncthreads();
    }
    if (t == 0) { kmax[row] = sm[0]; ksum[row] = ss[0]; }
}

// ---------------------------------------------------------------- K5: context partials
__global__ __launch_bounds__(256) void k_context(const float* __restrict__ qkv, const float* __restrict__ mem_kv,
                                                 const float* __restrict__ kmax, const float* __restrict__ ksum,
                                                 float* __restrict__ ctxp) {
    int bh = blockIdx.x;
    int p = blockIdx.y;
    int b = bh >> 3, h = bh & 7;
    const float* kp = qkv + ((size_t)b * NO3 + NHID + h * NDH) * NPIX;
    const float* vp = qkv + ((size_t)b * NO3 + 2 * NHID + h * NDH) * NPIX;
    __shared__ float KsT[64][68];
    __shared__ float VsT[64][68];
    __shared__ float smx[64], sinv[64];
    int t = threadIdx.x;
    if (t < 64) { smx[t] = kmax[bh * 64 + t]; sinv[t] = 1.0f / ksum[bh * 64 + t]; }
    __syncthreads();
    int tx = t & 15, ty = t >> 4;
    int d0 = ty * 4, e0 = tx * 4;
    float acc[4][4] = {{0.f}};
    if (p == 0) {
        const float* mkp = mem_kv + (size_t)h * 64 * 8;
        const float* mvp = mem_kv + (size_t)NHEADS * 64 * 8 + (size_t)h * 64 * 8;
        #pragma unroll
        for (int j = 0; j < 8; ++j) {
            float vv[4];
            #pragma unroll
            for (int q = 0; q < 4; ++q) vv[q] = mvp[(e0 + q) * 8 + j];
            #pragma unroll
            for (int i = 0; i < 4; ++i) {
                float kk = __expf(mkp[(d0 + i) * 8 + j] - smx[d0 + i]) * sinv[d0 + i];
                #pragma unroll
                for (int q = 0; q < 4; ++q) acc[i][q] = fmaf(kk, vv[q], acc[i][q]);
            }
        }
    }
    int rr = t >> 6, cc = t & 63;
    for (int n0 = p * 1024; n0 < p * 1024 + 1024; n0 += 64) {
        #pragma unroll
        for (int i = 0; i < 16; ++i) {
            int row = rr + i * 4;
            float kv = kp[(size_t)row * NPIX + n0 + cc];
            KsT[cc][row] = __expf(kv - smx[row]) * sinv[row];
            VsT[cc][row] = vp[(size_t)row * NPIX + n0 + cc];
        }
        __syncthreads();
        #pragma unroll 4
        for (int n = 0; n < 64; ++n) {
            float4 a = *(const float4*)&KsT[n][d0];
            float4 vv = *(const float4*)&VsT[n][e0];
            float av[4] = {a.x, a.y, a.z, a.w};
            float vvv[4] = {vv.x, vv.y, vv.z, vv.w};
            #pragma unroll
            for (int i = 0; i < 4; ++i)
                #pragma unroll
                for (int q = 0; q < 4; ++q) acc[i][q] = fmaf(av[i], vvv[q], acc[i][q]);
        }
        __syncthreads();
    }
    #pragma unroll
    for (int i = 0; i < 4; ++i)
        #pragma unroll
        for (int q = 0; q < 4; ++q)
            ctxp[(((size_t)p * 64 + bh) * 64 + d0 + i) * 64 + e0 + q] = acc[i][q];
}

// ---------------------------------------------------------------- K6: out'[n][c2] (bf16) = sum_d ctx[d,e]*q'[d,n]; over dead k region
__global__ __launch_bounds__(256) void k_pv(float* __restrict__ qkv, const float* __restrict__ ctxp) {
    int nb = blockIdx.x;
    int bh = blockIdx.y;
    int b = bh >> 3, h = bh & 7;
    __shared__ float Cs[64][64];
    int t = threadIdx.x;
    for (int i = t; i < 4096; i += 256) {
        float v = 0.f;
        #pragma unroll
        for (int p = 0; p < 4; ++p) v += ctxp[((size_t)p * 64 + bh) * 4096 + i];
        Cs[i >> 6][i & 63] = v;
    }
    __syncthreads();
    int n = nb * 256 + t;
    const float* qp = qkv + ((size_t)b * NO3 + h * NDH) * NPIX + n;
    float acc[64];
    #pragma unroll
    for (int e = 0; e < 64; ++e) acc[e] = 0.f;
    #pragma unroll 2
    for (int d = 0; d < 64; ++d) {
        float qv = qp[(size_t)d * NPIX];
        const float4* crow = (const float4*)&Cs[d][0];
        #pragma unroll
        for (int e4 = 0; e4 < 16; ++e4) {
            float4 cv = crow[e4];
            acc[e4 * 4 + 0] = fmaf(cv.x, qv, acc[e4 * 4 + 0]);
            acc[e4 * 4 + 1] = fmaf(cv.y, qv, acc[e4 * 4 + 1]);
            acc[e4 * 4 + 2] = fmaf(cv.z, qv, acc[e4 * 4 + 2]);
            acc[e4 * 4 + 3] = fmaf(cv.w, qv, acc[e4 * 4 + 3]);
        }
    }
    // bf16 [n][c2] rows into the dead k region (consumed already by k_context)
    u16* outT = (u16*)(qkv + ((size_t)b * NO3 + NHID) * NPIX);
    u16* op = outT + (size_t)n * NHID + h * NDH;
    #pragma unroll
    for (int e8 = 0; e8 < 8; ++e8) {
        union { u16 us[8]; uint4 v; } pk;
        #pragma unroll
        for (int u = 0; u < 8; ++u) pk.us[u] = f2bf(acc[e8 * 8 + u]);
        *(uint4*)(op + e8 * 8) = pk.v;
    }
}

// ---------------------------------------------------------------- K8: final RMS norm, in place on d_out
__global__ __launch_bounds__(256) void k_out_norm(float* __restrict__ out, const float* __restrict__ onw) {
    int idx = blockIdx.x * 256 + threadIdx.x;
    int b = idx >> 12, n = idx & 4095;
    float* op = out + (size_t)b * NC * NPIX + n;
    float acc = 0.f;
    #pragma unroll 8
    for (int c = 0; c < NC; ++c) { float v = op[(size_t)c * NPIX]; acc = fmaf(v, v, acc); }
    float sc = 16.0f / fmaxf(sqrtf(acc), 1e-12f);
    #pragma unroll 8
    for (int c = 0; c < NC; ++c) op[(size_t)c * NPIX] = op[(size_t)c * NPIX] * (sc * onw[c]);
}

extern "C" void kernel_launch(void* const* d_in, const int* in_sizes, int n_in,
                              void* d_out, int out_size, void* d_ws, size_t ws_size,
                              hipStream_t stream) {
    const float* x      = (const float*)d_in[0];
    const float* norm_w = (const float*)d_in[1];
    const float* w_qkv  = (const float*)d_in[2];
    const float* mem_kv = (const float*)d_in[3];
    const float* w_out  = (const float*)d_in[4];
    const float* b_out  = (const float*)d_in[5];
    const float* onw    = (const float*)d_in[6];
    float* out = (float*)d_out;
    float* ws  = (float*)d_ws;

    float* kmax = ws + WS_KMAX;
    float* ksum = ws + WS_KSUM;
    float* ctxp = ws + WS_CTXP;
    u16*   wqbf = (u16*)(ws + WS_WQBF);
    u16*   wobf = (u16*)(ws + WS_WOBF);
    float* qkv  = ws + WS_QKV;
    u16*   xbfT = (u16*)d_out;   // d_out is dead scratch until GEMM2 writes it
    const u16* outT = (const u16*)(qkv + (size_t)NHID * NPIX);   // per-batch stride NO3*NPIX floats

    k_wconv        <<<dim3(512),          dim3(256), 0, stream>>>(w_qkv, w_out, wqbf, wobf);
    k_scale_convert<<<dim3(NB * 64),      dim3(256), 0, stream>>>(x, norm_w, xbfT);
    k_mfma_nt<256, false><<<dim3(32, 12, NB), dim3(256), 0, stream>>>(
        wqbf, xbfT, nullptr, qkv, (size_t)NPIX * NC, (size_t)NO3 * NPIX);
    k_q_softmax    <<<dim3(NB * NHEADS * NPIX / 256), dim3(256), 0, stream>>>(qkv);
    k_k_stats      <<<dim3(NB * NHID),    dim3(256), 0, stream>>>(qkv, mem_kv, kmax, ksum);
    k_context      <<<dim3(NB * NHEADS, 4), dim3(256), 0, stream>>>(qkv, mem_kv, kmax, ksum, ctxp);
    k_pv           <<<dim3(16, NB * NHEADS), dim3(256), 0, stream>>>(qkv, ctxp);
    k_mfma_nt<512, true><<<dim3(32, 2, NB), dim3(256), 0, stream>>>(
        wobf, outT, b_out, out, (size_t)NO3 * NPIX * 2, (size_t)NC * NPIX);
    k_out_norm     <<<dim3(NB * NPIX / 256), dim3(256), 0, stream>>>(out, onw);
}

// Round 8
// 333.576 us; speedup vs baseline: 2.1745x; 1.0228x over previous
//
#include <hip/hip_runtime.h>
#include <math.h>

// Problem constants
#define NB 8        // batch
#define NC 256      // channels (DIM)
#define NPIX 4096   // H*W
#define NO3 1536    // 3*HIDDEN
#define NHID 512    // HIDDEN
#define NHEADS 8
#define NDH 64
#define NPART 16    // k_context n-partials

typedef unsigned short u16;
typedef __attribute__((ext_vector_type(8))) short short8;
typedef __attribute__((ext_vector_type(4))) float f32x4;

// Workspace layout (float offsets). qkv stays fp32 (precision guard for softmaxes).
// d_out doubles as scratch before GEMM2 writes it: first half xbfT (bf16 normalized
// input, 16.8MB), second half ctxp16 (16 context partials, 16.8MB). Both dead by GEMM2.
#define WS_KMAX  0          // [NB*NHID]
#define WS_KSUM  4096       // [NB*NHID]
#define WS_CTX   8192       // [64][64][64] reduced context (262144 floats)
#define WS_WQBF  1056768    // ushort[1536*256]  (as float region: 196608)
#define WS_WOBF  1253376    // ushort[256*512]   (as float region: 65536)
#define WS_QKV   1318912    // [NB][1536][4096] fp32
// total = 1318912 + 50331648 = 51,650,560 floats ~= 206.6 MB (proven budget)

__device__ __forceinline__ u16 f2bf(float f) {
    unsigned u = __builtin_bit_cast(unsigned, f);
    unsigned r = (u + 0x7FFFu + ((u >> 16) & 1u)) >> 16;   // RTN-even
    return (u16)r;
}

typedef const __attribute__((address_space(1))) unsigned int guint;
typedef __attribute__((address_space(3))) unsigned int luint;

// ---------------------------------------------------------------- K1: fused pixel-scale + transpose + bf16 convert
// xbfT[b][n][c] = bf16( x[b][c][n] * norm_w[c] * 16/max(||x[:,n]||,eps) )
__global__ __launch_bounds__(256) void k_scale_convert(const float* __restrict__ x,
                                                        const float* __restrict__ norm_w,
                                                        u16* __restrict__ xbfT) {
    __shared__ float xs[64][257];
    __shared__ float red[4][64];
    __shared__ float ssh[64];
    int blk = blockIdx.x;
    int b = blk >> 6;
    int n0 = (blk & 63) * 64;
    const float* xb = x + (size_t)b * NC * NPIX;
    int t = threadIdx.x;
    int p = t & 63, q = t >> 6;
    float accv = 0.f;
    #pragma unroll 8
    for (int c = q * 64; c < q * 64 + 64; ++c) {
        float v = xb[(size_t)c * NPIX + n0 + p];
        xs[p][c] = v;
        accv = fmaf(v, v, accv);
    }
    red[q][p] = accv;
    __syncthreads();
    if (t < 64) {
        float sum = red[0][t] + red[1][t] + red[2][t] + red[3][t];
        ssh[t] = 16.0f / fmaxf(sqrtf(sum), 1e-12f);
    }
    __syncthreads();
    int p2 = t >> 2, cbase = (t & 3) * 64;
    float sc = ssh[p2];
    u16* orow = xbfT + (size_t)(b * NPIX + n0 + p2) * NC + cbase;
    #pragma unroll
    for (int j = 0; j < 64; j += 8) {
        union { u16 us[8]; uint4 v; } pk;
        #pragma unroll
        for (int u = 0; u < 8; ++u)
            pk.us[u] = f2bf(xs[p2][cbase + j + u] * norm_w[cbase + j + u] * sc);
        *(uint4*)(orow + j) = pk.v;
    }
}

// ---------------------------------------------------------------- K2: weight bf16 convert (wq and wo)
__global__ __launch_bounds__(256) void k_wconv(const float* __restrict__ wq, const float* __restrict__ wo,
                                                u16* __restrict__ wqbf, u16* __restrict__ wobf) {
    int idx = blockIdx.x * 256 + threadIdx.x;
    int e = idx * 4;
    if (e < 393216) {
        float4 v = *(const float4*)(wq + e);
        union { u16 us[4]; uint2 v2; } pk;
        pk.us[0] = f2bf(v.x); pk.us[1] = f2bf(v.y); pk.us[2] = f2bf(v.z); pk.us[3] = f2bf(v.w);
        *(uint2*)(wqbf + e) = pk.v2;
    } else {
        int e2 = e - 393216;
        float4 v = *(const float4*)(wo + e2);
        union { u16 us[4]; uint2 v2; } pk;
        pk.us[0] = f2bf(v.x); pk.us[1] = f2bf(v.y); pk.us[2] = f2bf(v.z); pk.us[3] = f2bf(v.w);
        *(uint2*)(wobf + e2) = pk.v2;
    }
}

// ---------------------------------------------------------------- MFMA NT-GEMM (m97 structure)
template<int KD, bool BIAS>
__global__ __launch_bounds__(256) void k_mfma_nt(const u16* __restrict__ A, const u16* __restrict__ B,
                                                  const float* __restrict__ bias, float* __restrict__ C,
                                                  size_t bStride, size_t cStride) {
    __shared__ u16 lA[128 * 64];
    __shared__ u16 lB[128 * 64];
    const int b = blockIdx.z;
    const int m0 = blockIdx.y * 128;
    const int n0 = blockIdx.x * 128;
    const u16* Bb = B + (size_t)b * bStride;
    float* Cb = C + (size_t)b * cStride;
    const int t = threadIdx.x;
    const int lane = t & 63;
    const int wid = t >> 6;
    const int wr = (wid >> 1) * 64;
    const int wc = (wid & 1) * 64;
    const int fr = lane & 15;
    const int fq = lane >> 4;

    f32x4 acc[4][4];
    #pragma unroll
    for (int i = 0; i < 4; ++i)
        #pragma unroll
        for (int j = 0; j < 4; ++j) acc[i][j] = (f32x4){0.f, 0.f, 0.f, 0.f};

    for (int k0 = 0; k0 < KD; k0 += 64) {
        #pragma unroll
        for (int i = 0; i < 4; ++i) {
            int idx = i * 256 + t;
            int row = idx >> 3;
            int col = (idx & 7) * 8;
            __builtin_amdgcn_global_load_lds((guint*)(A + (size_t)(m0 + row) * KD + k0 + col),
                                             (luint*)(&lA[idx * 8]), 16, 0, 0);
            __builtin_amdgcn_global_load_lds((guint*)(Bb + (size_t)(n0 + row) * KD + k0 + col),
                                             (luint*)(&lB[idx * 8]), 16, 0, 0);
        }
        __syncthreads();
        #pragma unroll
        for (int kk = 0; kk < 2; ++kk) {
            short8 af[4], bfv[4];
            #pragma unroll
            for (int i = 0; i < 4; ++i)
                af[i] = *(const short8*)&lA[(wr + i * 16 + fr) * 64 + kk * 32 + fq * 8];
            #pragma unroll
            for (int j = 0; j < 4; ++j)
                bfv[j] = *(const short8*)&lB[(wc + j * 16 + fr) * 64 + kk * 32 + fq * 8];
            #pragma unroll
            for (int i = 0; i < 4; ++i)
                #pragma unroll
                for (int j = 0; j < 4; ++j)
                    acc[i][j] = __builtin_amdgcn_mfma_f32_16x16x32_bf16(af[i], bfv[j], acc[i][j], 0, 0, 0);
        }
        __syncthreads();
    }
    #pragma unroll
    for (int i = 0; i < 4; ++i) {
        int rbase = m0 + wr + i * 16 + fq * 4;
        #pragma unroll
        for (int j = 0; j < 4; ++j) {
            int c = n0 + wc + j * 16 + fr;
            #pragma unroll
            for (int r = 0; r < 4; ++r) {
                float v = acc[i][j][r];
                if (BIAS) v += bias[rbase + r];
                Cb[(size_t)(rbase + r) * NPIX + c] = v;
            }
        }
    }
}

// ---------------------------------------------------------------- K4: k-row stats over 4104
__global__ __launch_bounds__(256) void k_k_stats(const float* __restrict__ qkv, const float* __restrict__ mem_kv,
                                                 float* __restrict__ kmax, float* __restrict__ ksum) {
    int row = blockIdx.x;
    int b = row >> 9, hd = row & 511;
    int h = hd >> 6, d = hd & 63;
    const float* kp = qkv + ((size_t)b * NO3 + NHID + hd) * NPIX;
    int t = threadIdx.x;
    float m = -1e30f, sum = 0.f;
    for (int n = t; n < NPIX; n += 256) {
        float v = kp[n];
        if (v > m) { sum *= __expf(m - v); m = v; }
        sum += __expf(v - m);
    }
    if (t < 8) {
        float v = mem_kv[((size_t)h * 64 + d) * 8 + t];
        if (v > m) { sum *= __expf(m - v); m = v; }
        sum += __expf(v - m);
    }
    __shared__ float sm[256], ss[256];
    sm[t] = m; ss[t] = sum;
    __syncthreads();
    for (int st = 128; st > 0; st >>= 1) {
        if (t < st) {
            float m1 = sm[t], m2 = sm[t + st];
            float s1 = ss[t], s2 = ss[t + st];
            float mm = fmaxf(m1, m2);
            sm[t] = mm;
            ss[t] = s1 * __expf(m1 - mm) + s2 * __expf(m2 - mm);
        }
        __syncthreads();
    }
    if (t == 0) { kmax[row] = sm[0]; ksum[row] = ss[0]; }
}

// ---------------------------------------------------------------- K5: context partials (NPART=16 for occupancy)
__global__ __launch_bounds__(256) void k_context(const float* __restrict__ qkv, const float* __restrict__ mem_kv,
                                                 const float* __restrict__ kmax, const float* __restrict__ ksum,
                                                 float* __restrict__ ctxp) {
    int bh = blockIdx.x;                            // 64
    int p = blockIdx.y;                             // 16 n-partials of 256 cols
    int b = bh >> 3, h = bh & 7;
    const float* kp = qkv + ((size_t)b * NO3 + NHID + h * NDH) * NPIX;
    const float* vp = qkv + ((size_t)b * NO3 + 2 * NHID + h * NDH) * NPIX;
    __shared__ float KsT[64][68];
    __shared__ float VsT[64][68];
    __shared__ float smx[64], sinv[64];
    int t = threadIdx.x;
    if (t < 64) { smx[t] = kmax[bh * 64 + t]; sinv[t] = 1.0f / ksum[bh * 64 + t]; }
    __syncthreads();
    int tx = t & 15, ty = t >> 4;
    int d0 = ty * 4, e0 = tx * 4;
    float acc[4][4] = {{0.f}};
    if (p == 0) {
        const float* mkp = mem_kv + (size_t)h * 64 * 8;
        const float* mvp = mem_kv + (size_t)NHEADS * 64 * 8 + (size_t)h * 64 * 8;
        #pragma unroll
        for (int j = 0; j < 8; ++j) {
            float vv[4];
            #pragma unroll
            for (int q = 0; q < 4; ++q) vv[q] = mvp[(e0 + q) * 8 + j];
            #pragma unroll
            for (int i = 0; i < 4; ++i) {
                float kk = __expf(mkp[(d0 + i) * 8 + j] - smx[d0 + i]) * sinv[d0 + i];
                #pragma unroll
                for (int q = 0; q < 4; ++q) acc[i][q] = fmaf(kk, vv[q], acc[i][q]);
            }
        }
    }
    int rr = t >> 6, cc = t & 63;
    for (int n0 = p * 256; n0 < p * 256 + 256; n0 += 64) {
        #pragma unroll
        for (int i = 0; i < 16; ++i) {
            int row = rr + i * 4;
            float kv = kp[(size_t)row * NPIX + n0 + cc];
            KsT[cc][row] = __expf(kv - smx[row]) * sinv[row];
            VsT[cc][row] = vp[(size_t)row * NPIX + n0 + cc];
        }
        __syncthreads();
        #pragma unroll 4
        for (int n = 0; n < 64; ++n) {
            float4 a = *(const float4*)&KsT[n][d0];
            float4 vv = *(const float4*)&VsT[n][e0];
            float av[4] = {a.x, a.y, a.z, a.w};
            float vvv[4] = {vv.x, vv.y, vv.z, vv.w};
            #pragma unroll
            for (int i = 0; i < 4; ++i)
                #pragma unroll
                for (int q = 0; q < 4; ++q) acc[i][q] = fmaf(av[i], vvv[q], acc[i][q]);
        }
        __syncthreads();
    }
    #pragma unroll
    for (int i = 0; i < 4; ++i)
        #pragma unroll
        for (int q = 0; q < 4; ++q)
            ctxp[(((size_t)p * 64 + bh) * 64 + d0 + i) * 64 + e0 + q] = acc[i][q];
}

// ---------------------------------------------------------------- K5b: reduce 16 context partials -> ctx
__global__ __launch_bounds__(256) void k_ctx_reduce(const float* __restrict__ ctxp, float* __restrict__ ctx) {
    int idx = blockIdx.x * 256 + threadIdx.x;       // 262144 total
    float s = 0.f;
    #pragma unroll
    for (int p = 0; p < NPART; ++p) s += ctxp[(size_t)p * 262144 + idx];
    ctx[idx] = s;
}

// ---------------------------------------------------------------- K6: fused q-softmax + PV
// out'[n][c2] (bf16) = sum_d ctx[bh][d][e] * softmax_d(q)[d,n] * 1/8; into dead k region
__global__ __launch_bounds__(256) void k_pv(float* __restrict__ qkv, const float* __restrict__ ctx) {
    int nb = blockIdx.x;                            // 16 column blocks of 256
    int bh = blockIdx.y;                            // 64
    int b = bh >> 3, h = bh & 7;
    __shared__ float Cs[64][64];
    int t = threadIdx.x;
    for (int i = t; i < 4096; i += 256)
        Cs[i >> 6][i & 63] = ctx[(size_t)bh * 4096 + i];
    __syncthreads();
    int n = nb * 256 + t;
    const float* qp = qkv + ((size_t)b * NO3 + h * NDH) * NPIX + n;
    float qv[64];
    float mx = -1e30f;
    #pragma unroll
    for (int d = 0; d < 64; ++d) { qv[d] = qp[(size_t)d * NPIX]; mx = fmaxf(mx, qv[d]); }
    float sum = 0.f;
    #pragma unroll
    for (int d = 0; d < 64; ++d) { qv[d] = __expf(qv[d] - mx); sum += qv[d]; }
    float inv = 0.125f / sum;   // * dh^-0.5
    float acc[64];
    #pragma unroll
    for (int e = 0; e < 64; ++e) acc[e] = 0.f;
    #pragma unroll 2
    for (int d = 0; d < 64; ++d) {
        float w = qv[d] * inv;
        const float4* crow = (const float4*)&Cs[d][0];
        #pragma unroll
        for (int e4 = 0; e4 < 16; ++e4) {
            float4 cv = crow[e4];
            acc[e4 * 4 + 0] = fmaf(cv.x, w, acc[e4 * 4 + 0]);
            acc[e4 * 4 + 1] = fmaf(cv.y, w, acc[e4 * 4 + 1]);
            acc[e4 * 4 + 2] = fmaf(cv.z, w, acc[e4 * 4 + 2]);
            acc[e4 * 4 + 3] = fmaf(cv.w, w, acc[e4 * 4 + 3]);
        }
    }
    u16* outT = (u16*)(qkv + ((size_t)b * NO3 + NHID) * NPIX);
    u16* op = outT + (size_t)n * NHID + h * NDH;
    #pragma unroll
    for (int e8 = 0; e8 < 8; ++e8) {
        union { u16 us[8]; uint4 v; } pk;
        #pragma unroll
        for (int u = 0; u < 8; ++u) pk.us[u] = f2bf(acc[e8 * 8 + u]);
        *(uint4*)(op + e8 * 8) = pk.v;
    }
}

// ---------------------------------------------------------------- K8: final RMS norm, in place on d_out
__global__ __launch_bounds__(256) void k_out_norm(float* __restrict__ out, const float* __restrict__ onw) {
    int idx = blockIdx.x * 256 + threadIdx.x;
    int b = idx >> 12, n = idx & 4095;
    float* op = out + (size_t)b * NC * NPIX + n;
    float acc = 0.f;
    #pragma unroll 8
    for (int c = 0; c < NC; ++c) { float v = op[(size_t)c * NPIX]; acc = fmaf(v, v, acc); }
    float sc = 16.0f / fmaxf(sqrtf(acc), 1e-12f);
    #pragma unroll 8
    for (int c = 0; c < NC; ++c) op[(size_t)c * NPIX] = op[(size_t)c * NPIX] * (sc * onw[c]);
}

extern "C" void kernel_launch(void* const* d_in, const int* in_sizes, int n_in,
                              void* d_out, int out_size, void* d_ws, size_t ws_size,
                              hipStream_t stream) {
    const float* x      = (const float*)d_in[0];
    const float* norm_w = (const float*)d_in[1];
    const float* w_qkv  = (const float*)d_in[2];
    const float* mem_kv = (const float*)d_in[3];
    const float* w_out  = (const float*)d_in[4];
    const float* b_out  = (const float*)d_in[5];
    const float* onw    = (const float*)d_in[6];
    float* out = (float*)d_out;
    float* ws  = (float*)d_ws;

    float* kmax = ws + WS_KMAX;
    float* ksum = ws + WS_KSUM;
    float* ctx  = ws + WS_CTX;
    u16*   wqbf = (u16*)(ws + WS_WQBF);
    u16*   wobf = (u16*)(ws + WS_WOBF);
    float* qkv  = ws + WS_QKV;
    u16*   xbfT  = (u16*)d_out;                       // d_out 1st half: dead until GEMM2
    float* ctxp  = (float*)d_out + 4194304;           // d_out 2nd half: dead until GEMM2
    const u16* outT = (const u16*)(qkv + (size_t)NHID * NPIX);   // per-batch stride NO3*NPIX floats

    k_wconv        <<<dim3(512),            dim3(256), 0, stream>>>(w_qkv, w_out, wqbf, wobf);
    k_scale_convert<<<dim3(NB * 64),        dim3(256), 0, stream>>>(x, norm_w, xbfT);
    k_mfma_nt<256, false><<<dim3(32, 12, NB), dim3(256), 0, stream>>>(
        wqbf, xbfT, nullptr, qkv, (size_t)NPIX * NC, (size_t)NO3 * NPIX);
    k_k_stats      <<<dim3(NB * NHID),      dim3(256), 0, stream>>>(qkv, mem_kv, kmax, ksum);
    k_context      <<<dim3(NB * NHEADS, NPART), dim3(256), 0, stream>>>(qkv, mem_kv, kmax, ksum, ctxp);
    k_ctx_reduce   <<<dim3(1024),           dim3(256), 0, stream>>>(ctxp, ctx);
    k_pv           <<<dim3(16, NB * NHEADS), dim3(256), 0, stream>>>(qkv, ctx);
    k_mfma_nt<512, true><<<dim3(32, 2, NB), dim3(256), 0, stream>>>(
        wobf, outT, b_out, out, (size_t)NO3 * NPIX * 2, (size_t)NC * NPIX);
    k_out_norm     <<<dim3(NB * NPIX / 256), dim3(256), 0, stream>>>(out, onw);
}

// Round 11
// 316.256 us; speedup vs baseline: 2.2935x; 1.0548x over previous
//
#include <hip/hip_runtime.h>
#include <math.h>

// Problem constants
#define NB 8        // batch
#define NC 256      // channels (DIM)
#define NPIX 4096   // H*W
#define NO3 1536    // 3*HIDDEN
#define NHID 512    // HIDDEN
#define NHEADS 8
#define NDH 64
#define NPART 16    // k_context n-partials

typedef unsigned short u16;
typedef __attribute__((ext_vector_type(8))) short short8;
typedef __attribute__((ext_vector_type(4))) float f32x4;

// Workspace layout (float offsets). qkv stays fp32 (precision guard for softmaxes).
// d_out doubles as scratch before GEMM2 writes it: first half xbfT (bf16 normalized
// input, 16.8MB), second half ctxp16 (16 context partials, 16.8MB). Both dead by GEMM2.
#define WS_KMAX  0          // [NB*NHID]
#define WS_KSUM  4096       // [NB*NHID]
#define WS_CTX   8192       // [64][64][64] reduced context (262144 floats)
#define WS_WQBF  1056768    // ushort[1536*256]  (as float region: 196608)
#define WS_WOBF  1253376    // ushort[256*512]   (as float region: 65536)
#define WS_QKV   1318912    // [NB][1536][4096] fp32
// total = 1318912 + 50331648 = 51,650,560 floats ~= 206.6 MB (proven budget)

__device__ __forceinline__ u16 f2bf(float f) {
    unsigned u = __builtin_bit_cast(unsigned, f);
    unsigned r = (u + 0x7FFFu + ((u >> 16) & 1u)) >> 16;   // RTN-even
    return (u16)r;
}

typedef const __attribute__((address_space(1))) unsigned int guint;
typedef __attribute__((address_space(3))) unsigned int luint;

// ---------------------------------------------------------------- K1: fused pixel-scale + transpose + bf16 convert
__global__ __launch_bounds__(256) void k_scale_convert(const float* __restrict__ x,
                                                        const float* __restrict__ norm_w,
                                                        u16* __restrict__ xbfT) {
    __shared__ float xs[64][257];
    __shared__ float red[4][64];
    __shared__ float ssh[64];
    int blk = blockIdx.x;
    int b = blk >> 6;
    int n0 = (blk & 63) * 64;
    const float* xb = x + (size_t)b * NC * NPIX;
    int t = threadIdx.x;
    int p = t & 63, q = t >> 6;
    float accv = 0.f;
    #pragma unroll 8
    for (int c = q * 64; c < q * 64 + 64; ++c) {
        float v = xb[(size_t)c * NPIX + n0 + p];
        xs[p][c] = v;
        accv = fmaf(v, v, accv);
    }
    red[q][p] = accv;
    __syncthreads();
    if (t < 64) {
        float sum = red[0][t] + red[1][t] + red[2][t] + red[3][t];
        ssh[t] = 16.0f / fmaxf(sqrtf(sum), 1e-12f);
    }
    __syncthreads();
    int p2 = t >> 2, cbase = (t & 3) * 64;
    float sc = ssh[p2];
    u16* orow = xbfT + (size_t)(b * NPIX + n0 + p2) * NC + cbase;
    #pragma unroll
    for (int j = 0; j < 64; j += 8) {
        union { u16 us[8]; uint4 v; } pk;
        #pragma unroll
        for (int u = 0; u < 8; ++u)
            pk.us[u] = f2bf(xs[p2][cbase + j + u] * norm_w[cbase + j + u] * sc);
        *(uint4*)(orow + j) = pk.v;
    }
}

// ---------------------------------------------------------------- K2: weight bf16 convert (wq and wo)
__global__ __launch_bounds__(256) void k_wconv(const float* __restrict__ wq, const float* __restrict__ wo,
                                                u16* __restrict__ wqbf, u16* __restrict__ wobf) {
    int idx = blockIdx.x * 256 + threadIdx.x;
    int e = idx * 4;
    if (e < 393216) {
        float4 v = *(const float4*)(wq + e);
        union { u16 us[4]; uint2 v2; } pk;
        pk.us[0] = f2bf(v.x); pk.us[1] = f2bf(v.y); pk.us[2] = f2bf(v.z); pk.us[3] = f2bf(v.w);
        *(uint2*)(wqbf + e) = pk.v2;
    } else {
        int e2 = e - 393216;
        float4 v = *(const float4*)(wo + e2);
        union { u16 us[4]; uint2 v2; } pk;
        pk.us[0] = f2bf(v.x); pk.us[1] = f2bf(v.y); pk.us[2] = f2bf(v.z); pk.us[3] = f2bf(v.w);
        *(uint2*)(wobf + e2) = pk.v2;
    }
}

// ---------------------------------------------------------------- MFMA NT-GEMM (m97 structure)
template<int KD, bool BIAS>
__global__ __launch_bounds__(256) void k_mfma_nt(const u16* __restrict__ A, const u16* __restrict__ B,
                                                  const float* __restrict__ bias, float* __restrict__ C,
                                                  size_t bStride, size_t cStride) {
    __shared__ u16 lA[128 * 64];
    __shared__ u16 lB[128 * 64];
    const int b = blockIdx.z;
    const int m0 = blockIdx.y * 128;
    const int n0 = blockIdx.x * 128;
    const u16* Bb = B + (size_t)b * bStride;
    float* Cb = C + (size_t)b * cStride;
    const int t = threadIdx.x;
    const int lane = t & 63;
    const int wid = t >> 6;
    const int wr = (wid >> 1) * 64;
    const int wc = (wid & 1) * 64;
    const int fr = lane & 15;
    const int fq = lane >> 4;

    f32x4 acc[4][4];
    #pragma unroll
    for (int i = 0; i < 4; ++i)
        #pragma unroll
        for (int j = 0; j < 4; ++j) acc[i][j] = (f32x4){0.f, 0.f, 0.f, 0.f};

    for (int k0 = 0; k0 < KD; k0 += 64) {
        #pragma unroll
        for (int i = 0; i < 4; ++i) {
            int idx = i * 256 + t;
            int row = idx >> 3;
            int col = (idx & 7) * 8;
            __builtin_amdgcn_global_load_lds((guint*)(A + (size_t)(m0 + row) * KD + k0 + col),
                                             (luint*)(&lA[idx * 8]), 16, 0, 0);
            __builtin_amdgcn_global_load_lds((guint*)(Bb + (size_t)(n0 + row) * KD + k0 + col),
                                             (luint*)(&lB[idx * 8]), 16, 0, 0);
        }
        __syncthreads();
        #pragma unroll
        for (int kk = 0; kk < 2; ++kk) {
            short8 af[4], bfv[4];
            #pragma unroll
            for (int i = 0; i < 4; ++i)
                af[i] = *(const short8*)&lA[(wr + i * 16 + fr) * 64 + kk * 32 + fq * 8];
            #pragma unroll
            for (int j = 0; j < 4; ++j)
                bfv[j] = *(const short8*)&lB[(wc + j * 16 + fr) * 64 + kk * 32 + fq * 8];
            #pragma unroll
            for (int i = 0; i < 4; ++i)
                #pragma unroll
                for (int j = 0; j < 4; ++j)
                    acc[i][j] = __builtin_amdgcn_mfma_f32_16x16x32_bf16(af[i], bfv[j], acc[i][j], 0, 0, 0);
        }
        __syncthreads();
    }
    #pragma unroll
    for (int i = 0; i < 4; ++i) {
        int rbase = m0 + wr + i * 16 + fq * 4;
        #pragma unroll
        for (int j = 0; j < 4; ++j) {
            int c = n0 + wc + j * 16 + fr;
            #pragma unroll
            for (int r = 0; r < 4; ++r) {
                float v = acc[i][j][r];
                if (BIAS) v += bias[rbase + r];
                Cb[(size_t)(rbase + r) * NPIX + c] = v;
            }
        }
    }
}

// ---------------------------------------------------------------- K4: k-row stats over 4104
__global__ __launch_bounds__(256) void k_k_stats(const float* __restrict__ qkv, const float* __restrict__ mem_kv,
                                                 float* __restrict__ kmax, float* __restrict__ ksum) {
    int row = blockIdx.x;
    int b = row >> 9, hd = row & 511;
    int h = hd >> 6, d = hd & 63;
    const float* kp = qkv + ((size_t)b * NO3 + NHID + hd) * NPIX;
    int t = threadIdx.x;
    float m = -1e30f, sum = 0.f;
    for (int n = t; n < NPIX; n += 256) {
        float v = kp[n];
        if (v > m) { sum *= __expf(m - v); m = v; }
        sum += __expf(v - m);
    }
    if (t < 8) {
        float v = mem_kv[((size_t)h * 64 + d) * 8 + t];
        if (v > m) { sum *= __expf(m - v); m = v; }
        sum += __expf(v - m);
    }
    __shared__ float sm[256], ss[256];
    sm[t] = m; ss[t] = sum;
    __syncthreads();
    for (int st = 128; st > 0; st >>= 1) {
        if (t < st) {
            float m1 = sm[t], m2 = sm[t + st];
            float s1 = ss[t], s2 = ss[t + st];
            float mm = fmaxf(m1, m2);
            sm[t] = mm;
            ss[t] = s1 * __expf(m1 - mm) + s2 * __expf(m2 - mm);
        }
        __syncthreads();
    }
    if (t == 0) { kmax[row] = sm[0]; ksum[row] = ss[0]; }
}

// ---------------------------------------------------------------- K5: context partials (NPART=16 for occupancy)
__global__ __launch_bounds__(256) void k_context(const float* __restrict__ qkv, const float* __restrict__ mem_kv,
                                                 const float* __restrict__ kmax, const float* __restrict__ ksum,
                                                 float* __restrict__ ctxp) {
    int bh = blockIdx.x;
    int p = blockIdx.y;
    int b = bh >> 3, h = bh & 7;
    const float* kp = qkv + ((size_t)b * NO3 + NHID + h * NDH) * NPIX;
    const float* vp = qkv + ((size_t)b * NO3 + 2 * NHID + h * NDH) * NPIX;
    __shared__ float KsT[64][68];
    __shared__ float VsT[64][68];
    __shared__ float smx[64], sinv[64];
    int t = threadIdx.x;
    if (t < 64) { smx[t] = kmax[bh * 64 + t]; sinv[t] = 1.0f / ksum[bh * 64 + t]; }
    __syncthreads();
    int tx = t & 15, ty = t >> 4;
    int d0 = ty * 4, e0 = tx * 4;
    float acc[4][4] = {{0.f}};
    if (p == 0) {
        const float* mkp = mem_kv + (size_t)h * 64 * 8;
        const float* mvp = mem_kv + (size_t)NHEADS * 64 * 8 + (size_t)h * 64 * 8;
        #pragma unroll
        for (int j = 0; j < 8; ++j) {
            float vv[4];
            #pragma unroll
            for (int q = 0; q < 4; ++q) vv[q] = mvp[(e0 + q) * 8 + j];
            #pragma unroll
            for (int i = 0; i < 4; ++i) {
                float kk = __expf(mkp[(d0 + i) * 8 + j] - smx[d0 + i]) * sinv[d0 + i];
                #pragma unroll
                for (int q = 0; q < 4; ++q) acc[i][q] = fmaf(kk, vv[q], acc[i][q]);
            }
        }
    }
    int rr = t >> 6, cc = t & 63;
    for (int n0 = p * 256; n0 < p * 256 + 256; n0 += 64) {
        #pragma unroll
        for (int i = 0; i < 16; ++i) {
            int row = rr + i * 4;
            float kv = kp[(size_t)row * NPIX + n0 + cc];
            KsT[cc][row] = __expf(kv - smx[row]) * sinv[row];
            VsT[cc][row] = vp[(size_t)row * NPIX + n0 + cc];
        }
        __syncthreads();
        #pragma unroll 4
        for (int n = 0; n < 64; ++n) {
            float4 a = *(const float4*)&KsT[n][d0];
            float4 vv = *(const float4*)&VsT[n][e0];
            float av[4] = {a.x, a.y, a.z, a.w};
            float vvv[4] = {vv.x, vv.y, vv.z, vv.w};
            #pragma unroll
            for (int i = 0; i < 4; ++i)
                #pragma unroll
                for (int q = 0; q < 4; ++q) acc[i][q] = fmaf(av[i], vvv[q], acc[i][q]);
        }
        __syncthreads();
    }
    #pragma unroll
    for (int i = 0; i < 4; ++i)
        #pragma unroll
        for (int q = 0; q < 4; ++q)
            ctxp[(((size_t)p * 64 + bh) * 64 + d0 + i) * 64 + e0 + q] = acc[i][q];
}

// ---------------------------------------------------------------- K5b: reduce 16 context partials -> ctx
__global__ __launch_bounds__(256) void k_ctx_reduce(const float* __restrict__ ctxp, float* __restrict__ ctx) {
    int idx = blockIdx.x * 256 + threadIdx.x;
    float s = 0.f;
    #pragma unroll
    for (int p = 0; p < NPART; ++p) s += ctxp[(size_t)p * 262144 + idx];
    ctx[idx] = s;
}

// ---------------------------------------------------------------- K6: fused q-softmax + PV, spill-free
// Pass 1: online max+sum over d (no q storage). Pass 2: recompute exp, FMA into acc[64]
// (all static indices -> registers). q slice per block (64KB) is L2-resident for pass 2.
__global__ __launch_bounds__(256) void k_pv(float* __restrict__ qkv, const float* __restrict__ ctx) {
    int nb = blockIdx.x;                            // 16 column blocks of 256
    int bh = blockIdx.y;                            // 64
    int b = bh >> 3, h = bh & 7;
    __shared__ float Cs[64][64];
    int t = threadIdx.x;
    for (int i = t; i < 4096; i += 256)
        Cs[i >> 6][i & 63] = ctx[(size_t)bh * 4096 + i];
    __syncthreads();
    int n = nb * 256 + t;
    const float* qp = qkv + ((size_t)b * NO3 + h * NDH) * NPIX + n;
    // pass 1: branch-free online max + sum-exp
    float m = -1e30f, sum = 0.f;
    for (int d = 0; d < 64; ++d) {
        float v = qp[(size_t)d * NPIX];
        float mn = fmaxf(m, v);
        sum = sum * __expf(m - mn) + __expf(v - mn);
        m = mn;
    }
    float inv = 0.125f / sum;   // * dh^-0.5
    float acc[64];
    #pragma unroll
    for (int e = 0; e < 64; ++e) acc[e] = 0.f;
    // pass 2: recompute weights, accumulate (acc indices all static)
    for (int d = 0; d < 64; ++d) {
        float w = __expf(qp[(size_t)d * NPIX] - m) * inv;
        const float4* crow = (const float4*)&Cs[d][0];
        #pragma unroll
        for (int e4 = 0; e4 < 16; ++e4) {
            float4 cv = crow[e4];
            acc[e4 * 4 + 0] = fmaf(cv.x, w, acc[e4 * 4 + 0]);
            acc[e4 * 4 + 1] = fmaf(cv.y, w, acc[e4 * 4 + 1]);
            acc[e4 * 4 + 2] = fmaf(cv.z, w, acc[e4 * 4 + 2]);
            acc[e4 * 4 + 3] = fmaf(cv.w, w, acc[e4 * 4 + 3]);
        }
    }
    u16* outT = (u16*)(qkv + ((size_t)b * NO3 + NHID) * NPIX);
    u16* op = outT + (size_t)n * NHID + h * NDH;
    #pragma unroll
    for (int e8 = 0; e8 < 8; ++e8) {
        union { u16 us[8]; uint4 v; } pk;
        #pragma unroll
        for (int u = 0; u < 8; ++u) pk.us[u] = f2bf(acc[e8 * 8 + u]);
        *(uint4*)(op + e8 * 8) = pk.v;
    }
}

// ---------------------------------------------------------------- K8: final RMS norm, in place on d_out
__global__ __launch_bounds__(256) void k_out_norm(float* __restrict__ out, const float* __restrict__ onw) {
    int idx = blockIdx.x * 256 + threadIdx.x;
    int b = idx >> 12, n = idx & 4095;
    float* op = out + (size_t)b * NC * NPIX + n;
    float acc = 0.f;
    #pragma unroll 8
    for (int c = 0; c < NC; ++c) { float v = op[(size_t)c * NPIX]; acc = fmaf(v, v, acc); }
    float sc = 16.0f / fmaxf(sqrtf(acc), 1e-12f);
    #pragma unroll 8
    for (int c = 0; c < NC; ++c) op[(size_t)c * NPIX] = op[(size_t)c * NPIX] * (sc * onw[c]);
}

extern "C" void kernel_launch(void* const* d_in, const int* in_sizes, int n_in,
                              void* d_out, int out_size, void* d_ws, size_t ws_size,
                              hipStream_t stream) {
    const float* x      = (const float*)d_in[0];
    const float* norm_w = (const float*)d_in[1];
    const float* w_qkv  = (const float*)d_in[2];
    const float* mem_kv = (const float*)d_in[3];
    const float* w_out  = (const float*)d_in[4];
    const float* b_out  = (const float*)d_in[5];
    const float* onw    = (const float*)d_in[6];
    float* out = (float*)d_out;
    float* ws  = (float*)d_ws;

    float* kmax = ws + WS_KMAX;
    float* ksum = ws + WS_KSUM;
    float* ctx  = ws + WS_CTX;
    u16*   wqbf = (u16*)(ws + WS_WQBF);
    u16*   wobf = (u16*)(ws + WS_WOBF);
    float* qkv  = ws + WS_QKV;
    u16*   xbfT  = (u16*)d_out;                       // d_out 1st half: dead until GEMM2
    float* ctxp  = (float*)d_out + 4194304;           // d_out 2nd half: dead until GEMM2
    const u16* outT = (const u16*)(qkv + (size_t)NHID * NPIX);   // per-batch stride NO3*NPIX floats

    k_wconv        <<<dim3(512),            dim3(256), 0, stream>>>(w_qkv, w_out, wqbf, wobf);
    k_scale_convert<<<dim3(NB * 64),        dim3(256), 0, stream>>>(x, norm_w, xbfT);
    k_mfma_nt<256, false><<<dim3(32, 12, NB), dim3(256), 0, stream>>>(
        wqbf, xbfT, nullptr, qkv, (size_t)NPIX * NC, (size_t)NO3 * NPIX);
    k_k_stats      <<<dim3(NB * NHID),      dim3(256), 0, stream>>>(qkv, mem_kv, kmax, ksum);
    k_context      <<<dim3(NB * NHEADS, NPART), dim3(256), 0, stream>>>(qkv, mem_kv, kmax, ksum, ctxp);
    k_ctx_reduce   <<<dim3(1024),           dim3(256), 0, stream>>>(ctxp, ctx);
    k_pv           <<<dim3(16, NB * NHEADS), dim3(256), 0, stream>>>(qkv, ctx);
    k_mfma_nt<512, true><<<dim3(32, 2, NB), dim3(256), 0, stream>>>(
        wobf, outT, b_out, out, (size_t)NO3 * NPIX * 2, (size_t)NC * NPIX);
    k_out_norm     <<<dim3(NB * NPIX / 256), dim3(256), 0, stream>>>(out, onw);
}